// Round 16
// baseline (47.041 us; speedup 1.0000x reference)
//
#include <hip/hip_runtime.h>
#include <math.h>

#define BB 4096
#define CC 1000
#define DD 1024
#define NBLK 512           // exactly 512 blocks: 0..510 rows, 511 sort-only
#define SCALEF 100.0f

__device__ inline float wred(float v) {
#pragma unroll
    for (int o = 32; o > 0; o >>= 1) v += __shfl_down(v, o);
    return v;
}

__device__ inline float dot4(float4 a, float4 b) {
    return a.x * b.x + a.y * b.y + a.z * b.z + a.w * b.w;
}

union K1Shared {
    float accW[4][DD];  // 16KB: per-wave partial column sums (row blocks)
    struct {
        unsigned short tgt[BB];   // 8KB
        unsigned short ord[BB];   // 8KB  (stable sorted original indices)
        int wcnt[4][1024];        // 16KB: per-wave histograms -> running bases
        int wsum[4];
    } sort;                       // ~32KB
};

// K1: blocks 0..510: 8 rows each (blocks 0..7 take a 9th row on wave 0).
// Per row: p[b]=cos(f_b,q_{t_b}); block partial of S -> part[bid] (contiguous).
// Block 511: ballot-ranked stable counting sort ONLY (concurrent with rows),
// plus zeroes part[511].
__global__ __launch_bounds__(256) void k1(const float* __restrict__ feature,
                                          const float* __restrict__ query,
                                          const int* __restrict__ target,
                                          float* __restrict__ p,
                                          float* __restrict__ part,
                                          int* __restrict__ order,
                                          int* __restrict__ startsg,
                                          int* __restrict__ cntsg) {
    __shared__ K1Shared u;
    int tid = threadIdx.x, lane = tid & 63, wv = tid >> 6, bid = blockIdx.x;

    if (bid == NBLK - 1) {
        // ---- Phase A: load keys + per-wave histograms ----
        for (int i = tid; i < BB; i += 256) u.sort.tgt[i] = (unsigned short)target[i];
        for (int i = tid; i < 4096; i += 256) ((int*)u.sort.wcnt)[i] = 0;
        __syncthreads();
        {
            int base_i = wv * 1024;
            for (int r = 0; r < 16; ++r) {
                int c = u.sort.tgt[base_i + r * 64 + lane];
                atomicAdd(&u.sort.wcnt[wv][c], 1);
            }
        }
        __syncthreads();

        // ---- Phase B: scan -> class starts + per-wave bases (in wcnt) ----
        {
            int b4 = tid * 4;
            int w0[4], w1[4], w2[4], w3[4], t[4];
#pragma unroll
            for (int j = 0; j < 4; ++j) {
                int c = b4 + j;
                w0[j] = u.sort.wcnt[0][c];
                w1[j] = u.sort.wcnt[1][c];
                w2[j] = u.sort.wcnt[2][c];
                w3[j] = u.sort.wcnt[3][c];
                t[j] = w0[j] + w1[j] + w2[j] + w3[j];
            }
            int tot = t[0] + t[1] + t[2] + t[3];
            int inc = tot;
#pragma unroll
            for (int off = 1; off < 64; off <<= 1) {
                int s = __shfl_up(inc, off);
                if (lane >= off) inc += s;
            }
            if (lane == 63) u.sort.wsum[wv] = inc;
            __syncthreads();
            int wpre = 0;
            for (int w = 0; w < wv; ++w) wpre += u.sort.wsum[w];
            int excl = wpre + inc - tot;
            int pref = 0;
#pragma unroll
            for (int j = 0; j < 4; ++j) {
                int c = b4 + j;
                int e = excl + pref;
                pref += t[j];
                startsg[c] = e;
                cntsg[c] = t[j];
                u.sort.wcnt[0][c] = e;
                u.sort.wcnt[1][c] = e + w0[j];
                u.sort.wcnt[2][c] = e + w0[j] + w1[j];
                u.sort.wcnt[3][c] = e + w0[j] + w1[j] + w2[j];
            }
        }
        __syncthreads();

        // ---- Phase C: stable scatter, ballot-ranked, lane-ordered rounds ----
        {
            int base_i = wv * 1024;
            for (int r = 0; r < 16; ++r) {
                int idx = base_i + r * 64 + lane;
                int c = u.sort.tgt[idx];
                unsigned long long mask = ~0ull;
#pragma unroll
                for (int k = 0; k < 10; ++k) {
                    unsigned long long bal = __ballot((c >> k) & 1);
                    mask &= ((c >> k) & 1) ? bal : ~bal;
                }
                int rank = __popcll(mask & ((1ull << lane) - 1ull));
                int base = u.sort.wcnt[wv][c];
                u.sort.ord[base + rank] = (unsigned short)idx;
                if (rank == 0) u.sort.wcnt[wv][c] = base + __popcll(mask);
            }
        }
        __syncthreads();

        // ---- Phase D: write order; zero part[511] (unused row slot) ----
        for (int i = tid; i < BB; i += 256) order[i] = (int)u.sort.ord[i];
        ((float4*)part)[(NBLK - 1) * 256 + tid] = make_float4(0.f, 0.f, 0.f, 0.f);
        return;
    }

    // ---- row blocks: wave wv owns rows b0,b0+1; blocks 0..7 wave 0 take row 4088+bid ----
    float4 acc[4];
#pragma unroll
    for (int k = 0; k < 4; ++k) acc[k] = make_float4(0.f, 0.f, 0.f, 0.f);
    int b0 = bid * 8 + wv * 2;
    int rows[3];
    rows[0] = b0; rows[1] = b0 + 1;
    int nr = 2;
    if (bid < 8 && wv == 0) { rows[2] = 4088 + bid; nr = 3; }

    for (int r = 0; r < nr; ++r) {
        int b = rows[r];
        int tb = target[b];
        const float4* fr = (const float4*)(feature + (size_t)b * DD);
        const float4* qr = (const float4*)(query + (size_t)tb * DD);
        float4 x[4], q[4];
#pragma unroll
        for (int k = 0; k < 4; ++k) { x[k] = fr[lane + 64 * k]; q[k] = qr[lane + 64 * k]; }
        float nf = 0.f, nq = 0.f, dt = 0.f;
#pragma unroll
        for (int k = 0; k < 4; ++k) {
            nf += dot4(x[k], x[k]);
            nq += dot4(q[k], q[k]);
            dt += dot4(x[k], q[k]);
        }
        nf = wred(nf); nq = wred(nq); dt = wred(dt);
        nf = __shfl(nf, 0); nq = __shfl(nq, 0); dt = __shfl(dt, 0);
        float rn = rsqrtf(nf);
        if (lane == 0) p[b] = dt * rn * rsqrtf(nq);
#pragma unroll
        for (int k = 0; k < 4; ++k) {
            acc[k].x += x[k].x * rn; acc[k].y += x[k].y * rn;
            acc[k].z += x[k].z * rn; acc[k].w += x[k].w * rn;
        }
    }
#pragma unroll
    for (int k = 0; k < 4; ++k)
        ((float4*)&u.accW[wv][0])[lane + 64 * k] = acc[k];
    __syncthreads();
    // block combine + contiguous store (full cache lines, no amplification)
    {
        float4 a0 = ((const float4*)u.accW[0])[tid];
        float4 a1 = ((const float4*)u.accW[1])[tid];
        float4 a2 = ((const float4*)u.accW[2])[tid];
        float4 a3 = ((const float4*)u.accW[3])[tid];
        float4 s;
        s.x = a0.x + a1.x + a2.x + a3.x;
        s.y = a0.y + a1.y + a2.y + a3.y;
        s.z = a0.z + a1.z + a2.z + a3.z;
        s.w = a0.w + a1.w + a2.w + a3.w;
        ((float4*)part)[bid * 256 + tid] = s;
    }
}

// K2: 32 blocks; block g reduces part[512][1024] columns [g*32,(g+1)*32) -> S.
// Block 0 also resets the k3 finalize cells (visible to k3 via dispatch boundary).
__global__ __launch_bounds__(256) void k2(const float* __restrict__ part,
                                          float* __restrict__ S,
                                          float* __restrict__ accp,
                                          unsigned int* __restrict__ counter) {
    __shared__ float4 red[256];
    const float4* p4 = (const float4*)part;
    int g = blockIdx.x, tid = threadIdx.x;
    if (g == 0 && tid == 0) { *accp = 0.f; *counter = 0u; }
    int fc = g * 8 + (tid & 7);    // float4-column
    int rg = tid >> 3;             // row-group 0..31
    float4 a = make_float4(0.f, 0.f, 0.f, 0.f);
#pragma unroll
    for (int i = 0; i < 16; ++i) {
        int r = rg + 32 * i;
        float4 v = p4[r * 256 + fc];
        a.x += v.x; a.y += v.y; a.z += v.z; a.w += v.w;
    }
    red[tid] = a;
    __syncthreads();
#pragma unroll
    for (int s = 16; s >= 1; s >>= 1) {
        if (rg < s) {
            float4 o = red[tid + s * 8];
            float4 m = red[tid];
            m.x += o.x; m.y += o.y; m.z += o.z; m.w += o.w;
            red[tid] = m;
        }
        __syncthreads();
    }
    if (tid < 8) ((float4*)S)[g * 8 + tid] = red[tid];
}

// K3: block c: nnval[c] from S (4KB), class-c softplus partial -> atomicAdd(accp);
// last-finished block writes out (R6-proven done-counter finalize).
__global__ __launch_bounds__(256) void k3(const float* __restrict__ query,
                                          const float* __restrict__ S,
                                          const float* __restrict__ p,
                                          const int* __restrict__ order,
                                          const int* __restrict__ startsg,
                                          const int* __restrict__ cntsg,
                                          float* __restrict__ accp,
                                          unsigned int* __restrict__ counter,
                                          float* __restrict__ out) {
    __shared__ float red[4][2];
    __shared__ float rbc[4];
    int c = blockIdx.x, tid = threadIdx.x, lane = tid & 63, wv = tid >> 6;

    float4 s = ((const float4*)S)[tid];
    float4 q = ((const float4*)(query + (size_t)c * DD))[tid];
    float nq = dot4(q, q);
    float dt = dot4(q, s);
    nq = wred(nq); dt = wred(dt);
    if (lane == 0) { red[wv][0] = nq; red[wv][1] = dt; }
    __syncthreads();
    nq = red[0][0] + red[1][0] + red[2][0] + red[3][0];
    dt = red[0][1] + red[1][1] + red[2][1] + red[3][1];
    float nn = (10.0f / (float)BB) * dt * rsqrtf(nq);

    int s0 = startsg[c], n = cntsg[c];
    float partl = 0.f;
    for (int j = tid; j < n; j += 256) {
        int i = order[s0 + j];   // sample with target == c
        int oi = order[i];       // perm[i]
        float d = SCALEF * (nn - p[oi]);
        partl += (d > 0.f) ? (d + log1pf(expf(-d))) : log1pf(expf(d));
    }
    partl = wred(partl);
    if (lane == 0) rbc[wv] = partl;
    __syncthreads();
    if (tid == 0) {
        float tot = rbc[0] + rbc[1] + rbc[2] + rbc[3];
        atomicAdd(accp, tot);
        __threadfence();
        unsigned int old = atomicAdd(counter, 1u);
        if (old == (unsigned int)(CC - 1)) {
            float a = __hip_atomic_load(accp, __ATOMIC_ACQUIRE, __HIP_MEMORY_SCOPE_AGENT);
            out[0] = a / (float)BB;
        }
    }
}

extern "C" void kernel_launch(void* const* d_in, const int* in_sizes, int n_in,
                              void* d_out, int out_size, void* d_ws, size_t ws_size,
                              hipStream_t stream) {
    const float* feature = (const float*)d_in[0];
    const float* query   = (const float*)d_in[1];
    const int*   target  = (const int*)d_in[2];
    float* out = (float*)d_out;
    float* ws  = (float*)d_ws;

    float*        p       = ws;                          // 4096
    int*          order   = (int*)(ws + 4096);           // 4096
    int*          startsg = (int*)(ws + 8192);           // 1024
    int*          cntsg   = (int*)(ws + 9216);           // 1024
    float*        accp    = ws + 10240;                  // 1
    unsigned int* counter = (unsigned int*)(ws + 10244); // 1
    float*        S       = ws + 11264;                  // 1024
    float*        part    = ws + 16384;                  // 512*1024 floats (2MB)

    k1<<<NBLK, 256, 0, stream>>>(feature, query, target, p, part, order, startsg, cntsg);
    k2<<<32, 256, 0, stream>>>(part, S, accp, counter);
    k3<<<CC, 256, 0, stream>>>(query, S, p, order, startsg, cntsg, accp, counter, out);
}

// Round 17
// 25.146 us; speedup vs baseline: 1.8707x; 1.8707x over previous
//
#include <hip/hip_runtime.h>
#include <math.h>

#define BB 4096
#define CC 1000
#define DD 1024
#define NBLK 512           // exactly 512 blocks: 0..510 rows, 511 sort-only
#define SCALEF 100.0f

__device__ inline float wred(float v) {
#pragma unroll
    for (int o = 32; o > 0; o >>= 1) v += __shfl_down(v, o);
    return v;
}

__device__ inline float dot4(float4 a, float4 b) {
    return a.x * b.x + a.y * b.y + a.z * b.z + a.w * b.w;
}

union K1Shared {
    float accW[4][DD];  // 16KB: per-wave partial column sums (row blocks)
    struct {
        unsigned short tgt[BB];   // 8KB
        unsigned short ord[BB];   // 8KB  (stable sorted original indices)
        int wcnt[4][1024];        // 16KB: per-wave histograms -> running bases
        int wsum[4];
    } sort;                       // ~32KB
};

// K1: blocks 0..510: 8 rows each (blocks 0..7 take a 9th row on wave 0).
// Per row: p[b]=cos(f_b,q_{t_b}); block partial of S -> part[bid] (contiguous).
// Block 511: ballot-ranked stable counting sort ONLY (concurrent with rows),
// plus zeroes part[511].
__global__ __launch_bounds__(256) void k1(const float* __restrict__ feature,
                                          const float* __restrict__ query,
                                          const int* __restrict__ target,
                                          float* __restrict__ p,
                                          float* __restrict__ part,
                                          int* __restrict__ order,
                                          int* __restrict__ startsg,
                                          int* __restrict__ cntsg) {
    __shared__ K1Shared u;
    int tid = threadIdx.x, lane = tid & 63, wv = tid >> 6, bid = blockIdx.x;

    if (bid == NBLK - 1) {
        // ---- Phase A: load keys + per-wave histograms ----
        for (int i = tid; i < BB; i += 256) u.sort.tgt[i] = (unsigned short)target[i];
        for (int i = tid; i < 4096; i += 256) ((int*)u.sort.wcnt)[i] = 0;
        __syncthreads();
        {
            int base_i = wv * 1024;
            for (int r = 0; r < 16; ++r) {
                int c = u.sort.tgt[base_i + r * 64 + lane];
                atomicAdd(&u.sort.wcnt[wv][c], 1);
            }
        }
        __syncthreads();

        // ---- Phase B: scan -> class starts + per-wave bases (in wcnt) ----
        {
            int b4 = tid * 4;
            int w0[4], w1[4], w2[4], w3[4], t[4];
#pragma unroll
            for (int j = 0; j < 4; ++j) {
                int c = b4 + j;
                w0[j] = u.sort.wcnt[0][c];
                w1[j] = u.sort.wcnt[1][c];
                w2[j] = u.sort.wcnt[2][c];
                w3[j] = u.sort.wcnt[3][c];
                t[j] = w0[j] + w1[j] + w2[j] + w3[j];
            }
            int tot = t[0] + t[1] + t[2] + t[3];
            int inc = tot;
#pragma unroll
            for (int off = 1; off < 64; off <<= 1) {
                int s = __shfl_up(inc, off);
                if (lane >= off) inc += s;
            }
            if (lane == 63) u.sort.wsum[wv] = inc;
            __syncthreads();
            int wpre = 0;
            for (int w = 0; w < wv; ++w) wpre += u.sort.wsum[w];
            int excl = wpre + inc - tot;
            int pref = 0;
#pragma unroll
            for (int j = 0; j < 4; ++j) {
                int c = b4 + j;
                int e = excl + pref;
                pref += t[j];
                startsg[c] = e;
                cntsg[c] = t[j];
                u.sort.wcnt[0][c] = e;
                u.sort.wcnt[1][c] = e + w0[j];
                u.sort.wcnt[2][c] = e + w0[j] + w1[j];
                u.sort.wcnt[3][c] = e + w0[j] + w1[j] + w2[j];
            }
        }
        __syncthreads();

        // ---- Phase C: stable scatter, ballot-ranked, lane-ordered rounds ----
        {
            int base_i = wv * 1024;
            for (int r = 0; r < 16; ++r) {
                int idx = base_i + r * 64 + lane;
                int c = u.sort.tgt[idx];
                unsigned long long mask = ~0ull;
#pragma unroll
                for (int k = 0; k < 10; ++k) {
                    unsigned long long bal = __ballot((c >> k) & 1);
                    mask &= ((c >> k) & 1) ? bal : ~bal;
                }
                int rank = __popcll(mask & ((1ull << lane) - 1ull));
                int base = u.sort.wcnt[wv][c];
                u.sort.ord[base + rank] = (unsigned short)idx;
                if (rank == 0) u.sort.wcnt[wv][c] = base + __popcll(mask);
            }
        }
        __syncthreads();

        // ---- Phase D: write order; zero part[511] (unused row slot) ----
        for (int i = tid; i < BB; i += 256) order[i] = (int)u.sort.ord[i];
        ((float4*)part)[(NBLK - 1) * 256 + tid] = make_float4(0.f, 0.f, 0.f, 0.f);
        return;
    }

    // ---- row blocks: wave wv owns rows b0,b0+1; blocks 0..7 wave 0 take row 4088+bid ----
    float4 acc[4];
#pragma unroll
    for (int k = 0; k < 4; ++k) acc[k] = make_float4(0.f, 0.f, 0.f, 0.f);
    int b0 = bid * 8 + wv * 2;
    int rows[3];
    rows[0] = b0; rows[1] = b0 + 1;
    int nr = 2;
    if (bid < 8 && wv == 0) { rows[2] = 4088 + bid; nr = 3; }

    for (int r = 0; r < nr; ++r) {
        int b = rows[r];
        int tb = target[b];
        const float4* fr = (const float4*)(feature + (size_t)b * DD);
        const float4* qr = (const float4*)(query + (size_t)tb * DD);
        float4 x[4], q[4];
#pragma unroll
        for (int k = 0; k < 4; ++k) { x[k] = fr[lane + 64 * k]; q[k] = qr[lane + 64 * k]; }
        float nf = 0.f, nq = 0.f, dt = 0.f;
#pragma unroll
        for (int k = 0; k < 4; ++k) {
            nf += dot4(x[k], x[k]);
            nq += dot4(q[k], q[k]);
            dt += dot4(x[k], q[k]);
        }
        nf = wred(nf); nq = wred(nq); dt = wred(dt);
        nf = __shfl(nf, 0); nq = __shfl(nq, 0); dt = __shfl(dt, 0);
        float rn = rsqrtf(nf);
        if (lane == 0) p[b] = dt * rn * rsqrtf(nq);
#pragma unroll
        for (int k = 0; k < 4; ++k) {
            acc[k].x += x[k].x * rn; acc[k].y += x[k].y * rn;
            acc[k].z += x[k].z * rn; acc[k].w += x[k].w * rn;
        }
    }
#pragma unroll
    for (int k = 0; k < 4; ++k)
        ((float4*)&u.accW[wv][0])[lane + 64 * k] = acc[k];
    __syncthreads();
    // block combine + contiguous store (full cache lines, no amplification)
    {
        float4 a0 = ((const float4*)u.accW[0])[tid];
        float4 a1 = ((const float4*)u.accW[1])[tid];
        float4 a2 = ((const float4*)u.accW[2])[tid];
        float4 a3 = ((const float4*)u.accW[3])[tid];
        float4 s;
        s.x = a0.x + a1.x + a2.x + a3.x;
        s.y = a0.y + a1.y + a2.y + a3.y;
        s.z = a0.z + a1.z + a2.z + a3.z;
        s.w = a0.w + a1.w + a2.w + a3.w;
        ((float4*)part)[bid * 256 + tid] = s;
    }
}

// K2: 32 blocks; block g reduces part[512][1024] columns [g*32,(g+1)*32) -> S directly.
__global__ __launch_bounds__(256) void k2(const float* __restrict__ part,
                                          float* __restrict__ S) {
    __shared__ float4 red[256];
    const float4* p4 = (const float4*)part;
    int g = blockIdx.x, tid = threadIdx.x;
    int fc = g * 8 + (tid & 7);    // float4-column
    int rg = tid >> 3;             // row-group 0..31
    float4 a = make_float4(0.f, 0.f, 0.f, 0.f);
#pragma unroll
    for (int i = 0; i < 16; ++i) {
        int r = rg + 32 * i;
        float4 v = p4[r * 256 + fc];
        a.x += v.x; a.y += v.y; a.z += v.z; a.w += v.w;
    }
    red[tid] = a;
    __syncthreads();
#pragma unroll
    for (int s = 16; s >= 1; s >>= 1) {
        if (rg < s) {
            float4 o = red[tid + s * 8];
            float4 m = red[tid];
            m.x += o.x; m.y += o.y; m.z += o.z; m.w += o.w;
            red[tid] = m;
        }
        __syncthreads();
    }
    if (tid < 8) ((float4*)S)[g * 8 + tid] = red[tid];
}

// K3: 250 blocks, 4 classes each (one per wave). S staged in LDS once per block;
// nnval in-register; class-segment softplus partial -> lossp[c] (pure stores).
__global__ __launch_bounds__(256) void k3(const float* __restrict__ query,
                                          const float* __restrict__ S,
                                          const float* __restrict__ p,
                                          const int* __restrict__ order,
                                          const int* __restrict__ startsg,
                                          const int* __restrict__ cntsg,
                                          float* __restrict__ lossp) {
    __shared__ float S_lds[DD];
    int bid = blockIdx.x, tid = threadIdx.x, lane = tid & 63, wv = tid >> 6;

    ((float4*)S_lds)[tid] = ((const float4*)S)[tid];
    __syncthreads();

    int c = bid * 4 + wv;   // 250*4 = 1000 classes
    const float4* qr = (const float4*)(query + (size_t)c * DD);
    float nq = 0.f, dt = 0.f;
#pragma unroll
    for (int k = 0; k < 4; ++k) {
        float4 q = qr[lane + 64 * k];
        float4 sv = ((const float4*)S_lds)[lane + 64 * k];
        nq += dot4(q, q);
        dt += dot4(q, sv);
    }
    nq = wred(nq); dt = wred(dt);
    nq = __shfl(nq, 0); dt = __shfl(dt, 0);
    float nn = (10.0f / (float)BB) * dt * rsqrtf(nq);

    int s0 = startsg[c], n = cntsg[c];
    float partl = 0.f;
    for (int j = lane; j < n; j += 64) {
        int i = order[s0 + j];   // sample with target == c
        int oi = order[i];       // perm[i]
        float d = SCALEF * (nn - p[oi]);
        partl += (d > 0.f) ? (d + log1pf(expf(-d))) : log1pf(expf(d));
    }
    partl = wred(partl);
    if (lane == 0) lossp[c] = partl;
}

// K4: out = sum(lossp)/B
__global__ __launch_bounds__(256) void k4(const float* __restrict__ lossp,
                                          float* __restrict__ out) {
    __shared__ float rbc[4];
    int tid = threadIdx.x, lane = tid & 63, wv = tid >> 6;
    float a = 0.f;
    for (int j = tid; j < CC; j += 256) a += lossp[j];
    a = wred(a);
    if (lane == 0) rbc[wv] = a;
    __syncthreads();
    if (tid == 0) out[0] = (rbc[0] + rbc[1] + rbc[2] + rbc[3]) / (float)BB;
}

extern "C" void kernel_launch(void* const* d_in, const int* in_sizes, int n_in,
                              void* d_out, int out_size, void* d_ws, size_t ws_size,
                              hipStream_t stream) {
    const float* feature = (const float*)d_in[0];
    const float* query   = (const float*)d_in[1];
    const int*   target  = (const int*)d_in[2];
    float* out = (float*)d_out;
    float* ws  = (float*)d_ws;

    float* p       = ws;                      // 4096
    int*   order   = (int*)(ws + 4096);       // 4096
    int*   startsg = (int*)(ws + 8192);       // 1024
    int*   cntsg   = (int*)(ws + 9216);       // 1024
    float* lossp   = ws + 10240;              // 1024 (1000 used)
    float* S       = ws + 11264;              // 1024
    float* part    = ws + 16384;              // 512*1024 floats (2MB)

    k1<<<NBLK, 256, 0, stream>>>(feature, query, target, p, part, order, startsg, cntsg);
    k2<<<32, 256, 0, stream>>>(part, S);
    k3<<<250, 256, 0, stream>>>(query, S, p, order, startsg, cntsg, lossp);
    k4<<<1, 256, 0, stream>>>(lossp, out);
}